// Round 3
// baseline (910.438 us; speedup 1.0000x reference)
//
#include <hip/hip_runtime.h>
#include <hip/hip_bf16.h>

// Problem constants
#define KSZ 8192          // w_dim * d = flattened feature size
#define NB  64            // batch
#define NELEM (NB * KSZ)  // 524288 elements in x / q / k / v

typedef float  f32x4  __attribute__((ext_vector_type(4)));
typedef short  s16x8  __attribute__((ext_vector_type(8)));
typedef __bf16 bf16x8 __attribute__((ext_vector_type(8)));

// fp32 -> bf16 round-to-nearest-even (inputs are finite; no NaN handling needed)
__device__ __forceinline__ short f2bf(float f) {
    unsigned u = __builtin_bit_cast(unsigned, f);
    u += 0x7FFFu + ((u >> 16) & 1u);
    return (short)(u >> 16);
}

// ---------------------------------------------------------------------------
// Kernel 1: convert x (fp32) -> bf16 once; 1 MB result stays L2/L3-resident.
// 65536 threads, 8 elements each.
__global__ void cvt_kernel(const float* __restrict__ x, short* __restrict__ xb) {
    int i = blockIdx.x * 256 + threadIdx.x;
    const float4* xp = reinterpret_cast<const float4*>(x);
    float4 a = xp[2 * i], b = xp[2 * i + 1];
    s16x8 o;
    o[0] = f2bf(a.x); o[1] = f2bf(a.y); o[2] = f2bf(a.z); o[3] = f2bf(a.w);
    o[4] = f2bf(b.x); o[5] = f2bf(b.y); o[6] = f2bf(b.z); o[7] = f2bf(b.w);
    reinterpret_cast<s16x8*>(xb)[i] = o;
}

// ---------------------------------------------------------------------------
// Kernel 2: Q/K/V = x @ W^T + b   (M=64, N=8192, K=8192, weights streamed
// fp32 from HBM, converted to bf16 in-register, mfma_f32_16x16x32_bf16).
// grid = 3 * 256 = 768 blocks (exactly 3/CU), 256 threads (4 waves).
// Block tile: M=64 x N=32. Wave (wm,wn): m-half wm (2 frags), 16 n-cols.
// Per k-iteration a wave covers 16 W-rows x 128 consecutive bytes -> full
// cachelines, compulsory-only fetch (805 MB total).
__global__ __launch_bounds__(256) void qkv_gemm(
    const short* __restrict__ xb,
    const float* __restrict__ Wq, const float* __restrict__ Wk, const float* __restrict__ Wv,
    const float* __restrict__ bq, const float* __restrict__ bk, const float* __restrict__ bv,
    float* __restrict__ Qo, float* __restrict__ Ko, float* __restrict__ Vo)
{
    int bx = blockIdx.x;
    int t  = bx >> 8;              // 0..2 : which matrix
    int n0 = (bx & 255) * 32;      // n-tile base
    const float* W    = (t == 0) ? Wq : (t == 1) ? Wk : Wv;
    const float* bias = (t == 0) ? bq : (t == 1) ? bk : bv;
    float*       Out  = (t == 0) ? Qo : (t == 1) ? Ko : Vo;

    int tid  = threadIdx.x;
    int lane = tid & 63;
    int w    = tid >> 6;           // wave 0..3
    int wm   = w & 1;              // m-half (0: rows 0-31, 1: rows 32-63)
    int wn   = w >> 1;             // n-half (16 cols each)
    int l15  = lane & 15;
    int lg   = lane >> 4;          // k-group 0..3

    int ncol = n0 + wn * 16 + l15;                       // W row == output col
    const float* wp  = W + (size_t)ncol * KSZ + lg * 8;  // 8 consecutive k-floats/lane
    const short* ap0 = xb + (size_t)(wm * 32 + l15) * KSZ + lg * 8;
    const short* ap1 = ap0 + 16 * KSZ;

    f32x4 acc0 = {0.f, 0.f, 0.f, 0.f};
    f32x4 acc1 = {0.f, 0.f, 0.f, 0.f};

    #pragma unroll 4
    for (int k0 = 0; k0 < KSZ; k0 += 32) {
        float4 w0 = *reinterpret_cast<const float4*>(wp + k0);
        float4 w1 = *reinterpret_cast<const float4*>(wp + k0 + 4);
        s16x8  s0 = *reinterpret_cast<const s16x8*>(ap0 + k0);
        s16x8  s1 = *reinterpret_cast<const s16x8*>(ap1 + k0);
        s16x8  bs;
        bs[0] = f2bf(w0.x); bs[1] = f2bf(w0.y); bs[2] = f2bf(w0.z); bs[3] = f2bf(w0.w);
        bs[4] = f2bf(w1.x); bs[5] = f2bf(w1.y); bs[6] = f2bf(w1.z); bs[7] = f2bf(w1.w);
        bf16x8 bfr = __builtin_bit_cast(bf16x8, bs);
        bf16x8 a0  = __builtin_bit_cast(bf16x8, s0);
        bf16x8 a1  = __builtin_bit_cast(bf16x8, s1);
        acc0 = __builtin_amdgcn_mfma_f32_16x16x32_bf16(a0, bfr, acc0, 0, 0, 0);
        acc1 = __builtin_amdgcn_mfma_f32_16x16x32_bf16(a1, bfr, acc1, 0, 0, 0);
    }

    // C/D layout (m89-verified): col = lane&15 (n), row = (lane>>4)*4 + r (m)
    float  bval = bias[ncol];
    float* ob   = Out + (size_t)(wm * 32 + lg * 4) * KSZ + ncol;
    #pragma unroll
    for (int r = 0; r < 4; ++r) {
        ob[(size_t)r * KSZ]        = acc0[r] + bval;
        ob[(size_t)(r + 16) * KSZ] = acc1[r] + bval;
    }
}

// ---------------------------------------------------------------------------
// Softmax is over the QUERY axis: each (b, key-col) column normalizes over
// the 512 q-rows independently. Logits ~ N(0, 0.145), |max| ~ 0.8 over all
// samples -> exp without max-shift is numerically safe.
//
// Kernel 3 (pass A): rcs[b,k] = 1 / sum_q exp(score(q,k)); scores recomputed.
// grid = 64 b * 2 k-chunks, 256 threads; one k-column per thread.
// Q[b] (32 KB) staged in LDS; uniform-q reads broadcast (conflict-free).
#define ATT_SCALE 0.011048543456039806f   // 1/sqrt(8192)
__global__ __launch_bounds__(256) void colsum_kernel(
    const float* __restrict__ Q, const float* __restrict__ K, float* __restrict__ rcs)
{
    int b  = blockIdx.x >> 1;
    int kc = blockIdx.x & 1;
    int t  = threadIdx.x;

    __shared__ __align__(16) float Qs[512][16];   // 32 KB
    {
        const float4* qsrc = reinterpret_cast<const float4*>(Q + (size_t)b * KSZ) + t * 8;
        float4*       qdst = reinterpret_cast<float4*>(&Qs[0][0]) + t * 8;
        #pragma unroll
        for (int i = 0; i < 8; ++i) qdst[i] = qsrc[i];
    }
    int kcol = kc * 256 + t;
    const float4* kp = reinterpret_cast<const float4*>(K + (size_t)b * KSZ + (size_t)kcol * 16);
    float4 kA = kp[0], kB = kp[1], kC = kp[2], kD = kp[3];
    float kr[16] = {kA.x, kA.y, kA.z, kA.w, kB.x, kB.y, kB.z, kB.w,
                    kC.x, kC.y, kC.z, kC.w, kD.x, kD.y, kD.z, kD.w};
    __syncthreads();

    float cs0 = 0.f, cs1 = 0.f;   // two accumulators for ILP
    #pragma unroll 4
    for (int q = 0; q < 512; q += 2) {
        float s0 = 0.f, s1 = 0.f;
        #pragma unroll
        for (int d = 0; d < 16; ++d) {
            s0 = fmaf(Qs[q][d],     kr[d], s0);
            s1 = fmaf(Qs[q + 1][d], kr[d], s1);
        }
        cs0 += __expf(s0 * ATT_SCALE);
        cs1 += __expf(s1 * ATT_SCALE);
    }
    rcs[b * 512 + kcol] = 1.f / (cs0 + cs1);
}

// ---------------------------------------------------------------------------
// Kernel 4 (pass B): res[b,q,:] = sum_k exp(score(q,k))*rcs[k] * V[k,:];
// out = sigmoid(res) + x  (fused epilogue, writes d_out directly).
// grid = 64 b * 2 q-chunks, 256 threads; one q-row per thread (Q row + res
// in registers). K/V staged in LDS in two 256-column halves (34 KB total);
// uniform-k reads broadcast.
__global__ __launch_bounds__(256) void attnout_kernel(
    const float* __restrict__ Q, const float* __restrict__ K, const float* __restrict__ V,
    const float* __restrict__ rcs, const float* __restrict__ x, float* __restrict__ out)
{
    int b  = blockIdx.x >> 1;
    int qc = blockIdx.x & 1;
    int t  = threadIdx.x;
    int q  = qc * 256 + t;

    __shared__ __align__(16) float Kt[256][16];   // 16 KB
    __shared__ __align__(16) float Vt[256][16];   // 16 KB
    __shared__ float rs[512];                     // 2 KB

    rs[t]       = rcs[b * 512 + t];
    rs[t + 256] = rcs[b * 512 + 256 + t];

    float qreg[16];
    {
        const float4* qp = reinterpret_cast<const float4*>(Q + (size_t)b * KSZ + (size_t)q * 16);
        float4 a0 = qp[0], a1 = qp[1], a2 = qp[2], a3 = qp[3];
        qreg[0]  = a0.x; qreg[1]  = a0.y; qreg[2]  = a0.z; qreg[3]  = a0.w;
        qreg[4]  = a1.x; qreg[5]  = a1.y; qreg[6]  = a1.z; qreg[7]  = a1.w;
        qreg[8]  = a2.x; qreg[9]  = a2.y; qreg[10] = a2.z; qreg[11] = a2.w;
        qreg[12] = a3.x; qreg[13] = a3.y; qreg[14] = a3.z; qreg[15] = a3.w;
    }
    float res[16] = {};

    for (int h = 0; h < 2; ++h) {
        __syncthreads();   // protect Kt/Vt from previous half
        {
            const float4* ks = reinterpret_cast<const float4*>(K + (size_t)b * KSZ + h * 4096) + t * 4;
            const float4* vs = reinterpret_cast<const float4*>(V + (size_t)b * KSZ + h * 4096) + t * 4;
            float4*       kd = reinterpret_cast<float4*>(&Kt[0][0]) + t * 4;
            float4*       vd = reinterpret_cast<float4*>(&Vt[0][0]) + t * 4;
            #pragma unroll
            for (int i = 0; i < 4; ++i) { kd[i] = ks[i]; vd[i] = vs[i]; }
        }
        __syncthreads();

        #pragma unroll 2
        for (int kk = 0; kk < 256; ++kk) {
            float s = 0.f;
            #pragma unroll
            for (int d = 0; d < 16; ++d) s = fmaf(qreg[d], Kt[kk][d], s);
            float p = __expf(s * ATT_SCALE) * rs[h * 256 + kk];
            #pragma unroll
            for (int d = 0; d < 16; ++d) res[d] = fmaf(p, Vt[kk][d], res[d]);
        }
    }

    // epilogue: out = sigmoid(res) + x
    const float4* xp = reinterpret_cast<const float4*>(x + (size_t)b * KSZ + (size_t)q * 16);
    float4*       op = reinterpret_cast<float4*>(out + (size_t)b * KSZ + (size_t)q * 16);
    #pragma unroll
    for (int i = 0; i < 4; ++i) {
        float4 xi = xp[i];
        float4 o;
        o.x = 1.f / (1.f + __expf(-res[4 * i + 0])) + xi.x;
        o.y = 1.f / (1.f + __expf(-res[4 * i + 1])) + xi.y;
        o.z = 1.f / (1.f + __expf(-res[4 * i + 2])) + xi.z;
        o.w = 1.f / (1.f + __expf(-res[4 * i + 3])) + xi.w;
        op[i] = o;
    }
}

// ---------------------------------------------------------------------------
// Workspace layout (7.125 MB total — fits any plausible ws_size):
//   xb (bf16 x, 1 MB) | Q (2 MB) | K (2 MB) | V (2 MB) | rcs (128 KB)
extern "C" void kernel_launch(void* const* d_in, const int* in_sizes, int n_in,
                              void* d_out, int out_size, void* d_ws, size_t ws_size,
                              hipStream_t stream)
{
    const float* x  = (const float*)d_in[0];
    const float* Wq = (const float*)d_in[1];
    const float* bq = (const float*)d_in[2];
    const float* Wk = (const float*)d_in[3];
    const float* bk = (const float*)d_in[4];
    const float* Wv = (const float*)d_in[5];
    const float* bv = (const float*)d_in[6];
    float* out = (float*)d_out;

    char*  ws  = (char*)d_ws;
    short* xb  = (short*)ws;
    float* Qo  = (float*)(ws + (1u << 20));
    float* Ko  = Qo + NELEM;
    float* Vo  = Ko + NELEM;
    float* rcs = Vo + NELEM;

    hipLaunchKernelGGL(cvt_kernel,     dim3(256), dim3(256), 0, stream, x, xb);
    hipLaunchKernelGGL(qkv_gemm,       dim3(768), dim3(256), 0, stream,
                       xb, Wq, Wk, Wv, bq, bk, bv, Qo, Ko, Vo);
    hipLaunchKernelGGL(colsum_kernel,  dim3(128), dim3(256), 0, stream, Qo, Ko, rcs);
    hipLaunchKernelGGL(attnout_kernel, dim3(128), dim3(256), 0, stream, Qo, Ko, Vo, rcs, x, out);
}